// Round 3
// baseline (450.648 us; speedup 1.0000x reference)
//
#include <hip/hip_runtime.h>
#include <math.h>

// SSIM loss v3: column-streaming register kernel.
// Each thread owns ONE image column; streams down rows. Horizontal 11-tap in
// registers from aligned float4 global loads (shifted 16-tap weights absorb
// per-lane misalignment); vertical 11-tap via register FIR ring (static
// indices from 11-unrolled inner loop). No LDS for data, no barriers.
// Inputs: img1, img2 float32 [16,3,512,512]. Output: scalar float32.

#define IMG     512
#define NPLANES 48
#define NPIX    (48*512*512)
#define TS_Y    64
#define KSZ     11

__global__ void __launch_bounds__(256)
ssim_stream_kernel(const float* __restrict__ img1,
                   const float* __restrict__ img2,
                   float* __restrict__ acc)
{
    __shared__ float wsum[4];

    const int tid = threadIdx.x;
    const int c   = blockIdx.x * 256 + tid;       // this thread's column
    const int r0  = blockIdx.y * TS_Y;            // first output row of strip
    const int hs  = r0 - 5;                       // first h-row processed
    const size_t pbase = (size_t)blockIdx.z * IMG * IMG;
    const float* __restrict__ p1 = img1 + pbase;
    const float* __restrict__ p2 = img2 + pbase;

    // ---- Gaussian weights (one-time) ----
    float w[KSZ];
    {
        float s = 0.f;
#pragma unroll
        for (int i = 0; i < KSZ; ++i) {
            float d = (float)(i - 5);
            w[i] = expf(-(d * d) / 4.5f);
            s += w[i];
        }
        float inv = 1.f / s;
#pragma unroll
        for (int i = 0; i < KSZ; ++i) w[i] *= inv;
    }

    // ---- shifted 16-tap horizontal weights (absorb alignment offset) ----
    // window cols c-5..c+5 live at buf[o..o+10] where o=(c-5)&3.
    const int o  = (c - 5) & 3;
    const int a0 = (c - 5) - o;                   // 4-aligned base column
    float W[16];
#pragma unroll
    for (int t = 0; t < 16; ++t) {
        float v = 0.f;
        if (t <= 10)           v = (o == 0) ? w[t]     : v;
        if (t >= 1 && t <= 11) v = (o == 1) ? w[t - 1] : v;
        if (t >= 2 && t <= 12) v = (o == 2) ? w[t - 2] : v;
        if (t >= 3 && t <= 13) v = (o == 3) ? w[t - 3] : v;
        W[t] = v;
    }
    const bool ok0 = (a0      >= 0) && (a0      <= IMG - 4);
    const bool ok1 = (a0 + 4  >= 0) && (a0 + 4  <= IMG - 4);
    const bool ok2 =                   (a0 + 8  <= IMG - 4);
    const bool ok3 =                   (a0 + 12 <= IMG - 4);

    // ---- vertical FIR ring: 11 slots x 5 stats ----
    float ring[11][5];
#pragma unroll
    for (int i = 0; i < 11; ++i)
#pragma unroll
        for (int q = 0; q < 5; ++q) ring[i][q] = 0.f;

    const float C1 = 1e-4f;
    const float C2 = 9e-4f;
    float local = 0.f;

    for (int g = 0; g < 7; ++g) {               // 7 x 11 = 77 steps (74 used)
#pragma unroll
        for (int j = 0; j < 11; ++j) {
            const int s  = g * 11 + j;
            const int hr = hs + s;
            int hrc = hr < 0 ? 0 : (hr > IMG - 1 ? IMG - 1 : hr);
            const float* __restrict__ r1 = p1 + (size_t)hrc * IMG;
            const float* __restrict__ r2 = p2 + (size_t)hrc * IMG;

            float b1[16], b2[16];
#pragma unroll
            for (int t = 0; t < 16; ++t) { b1[t] = 0.f; b2[t] = 0.f; }
            if (ok0) { float4 v = *(const float4*)(r1 + a0);
                       b1[0] = v.x; b1[1] = v.y; b1[2]  = v.z; b1[3]  = v.w;
                       float4 u = *(const float4*)(r2 + a0);
                       b2[0] = u.x; b2[1] = u.y; b2[2]  = u.z; b2[3]  = u.w; }
            if (ok1) { float4 v = *(const float4*)(r1 + a0 + 4);
                       b1[4] = v.x; b1[5] = v.y; b1[6]  = v.z; b1[7]  = v.w;
                       float4 u = *(const float4*)(r2 + a0 + 4);
                       b2[4] = u.x; b2[5] = u.y; b2[6]  = u.z; b2[7]  = u.w; }
            if (ok2) { float4 v = *(const float4*)(r1 + a0 + 8);
                       b1[8] = v.x; b1[9] = v.y; b1[10] = v.z; b1[11] = v.w;
                       float4 u = *(const float4*)(r2 + a0 + 8);
                       b2[8] = u.x; b2[9] = u.y; b2[10] = u.z; b2[11] = u.w; }
            if (ok3) { float4 v = *(const float4*)(r1 + a0 + 12);
                       b1[12] = v.x; b1[13] = v.y; b1[14] = v.z; b1[15] = v.w;
                       float4 u = *(const float4*)(r2 + a0 + 12);
                       b2[12] = u.x; b2[13] = u.y; b2[14] = u.z; b2[15] = u.w; }

            // horizontal 16-tap (11 nonzero) over 5 statistics
            float st0 = 0.f, st1 = 0.f, st2 = 0.f, st3 = 0.f, st4 = 0.f;
#pragma unroll
            for (int t = 0; t < 16; ++t) {
                float x  = b1[t], y = b2[t];
                float Wx = W[t] * x;
                float Wy = W[t] * y;
                st0 += Wx;
                st1 += Wy;
                st2 += Wx * x;
                st3 += Wy * y;
                st4 += Wx * y;
            }
            // zero contribution from rows outside the image / past the strip
            float m = (((unsigned)hr < (unsigned)IMG) && (s < 74)) ? 1.f : 0.f;
            st0 *= m; st1 *= m; st2 *= m; st3 *= m; st4 *= m;

            // vertical ring update: slot (j+i)%11 holds output row hr-5+i
#pragma unroll
            for (int i = 0; i < 10; ++i) {
                const int   sl = (j + i) % 11;
                const float wv = w[10 - i];
                ring[sl][0] += wv * st0;
                ring[sl][1] += wv * st1;
                ring[sl][2] += wv * st2;
                ring[sl][3] += wv * st3;
                ring[sl][4] += wv * st4;
            }
            {
                const int   sl = (j + 10) % 11;
                const float wv = w[0];
                ring[sl][0] = wv * st0;   // fresh slot: overwrite, no add
                ring[sl][1] = wv * st1;
                ring[sl][2] = wv * st2;
                ring[sl][3] = wv * st3;
                ring[sl][4] = wv * st4;
            }

            // emit output row o = hr-5 (slot j), valid for s in [10, 73]
            if (s >= 10 && s <= 73) {
                float mu1 = ring[j][0], mu2 = ring[j][1];
                float v11 = ring[j][2], v22 = ring[j][3], v12 = ring[j][4];
                float mu1sq = mu1 * mu1;
                float mu2sq = mu2 * mu2;
                float mu12  = mu1 * mu2;
                float sig1  = v11 - mu1sq;
                float sig2  = v22 - mu2sq;
                float sig12 = v12 - mu12;
                float num = (2.f * mu12 + C1) * (2.f * sig12 + C2);
                float den = (mu1sq + mu2sq + C1) * (sig1 + sig2 + C2);
                local += num / den;
            }
        }
    }

    // ---- block reduction ----
#pragma unroll
    for (int off = 32; off > 0; off >>= 1)
        local += __shfl_down(local, off, 64);
    if ((tid & 63) == 0) wsum[tid >> 6] = local;
    __syncthreads();
    if (tid == 0) {
        float t = wsum[0] + wsum[1] + wsum[2] + wsum[3];
        atomicAdd(acc, t);
    }
}

__global__ void zero_acc_kernel(float* acc) {
    if (threadIdx.x == 0) acc[0] = 0.f;
}

__global__ void finalize_kernel(const float* __restrict__ acc,
                                float* __restrict__ out) {
    if (threadIdx.x == 0)
        out[0] = 1.0f - acc[0] * (1.0f / (float)NPIX);
}

extern "C" void kernel_launch(void* const* d_in, const int* in_sizes, int n_in,
                              void* d_out, int out_size, void* d_ws, size_t ws_size,
                              hipStream_t stream) {
    const float* img1 = (const float*)d_in[0];
    const float* img2 = (const float*)d_in[1];
    float* out = (float*)d_out;
    float* acc = (float*)d_ws;

    zero_acc_kernel<<<1, 64, 0, stream>>>(acc);
    dim3 grid(IMG / 256, IMG / TS_Y, NPLANES);   // (2, 8, 48) = 768 blocks
    ssim_stream_kernel<<<grid, 256, 0, stream>>>(img1, img2, acc);
    finalize_kernel<<<1, 64, 0, stream>>>(acc, out);
}

// Round 5
// 245.984 us; speedup vs baseline: 1.8320x; 1.8320x over previous
//
#include <hip/hip_runtime.h>
#include <math.h>

// SSIM loss v4 (resubmit after infra failure): v2 structure (global float4 ->
// horiz pass -> LDS stats -> vert pass + SSIM) with phase B using ALL 256
// threads (2col x 4row items, float2 LDS reads, static-index accumulators).
// One barrier between phases.
// Inputs: img1, img2 float32 [16,3,512,512]. Output: scalar float32.

#define TSX   64
#define TSY   32
#define LTY   42               // TSY + 10 rows of horizontal stats
#define IMG   512
#define NPLANES 48
#define NPIX  (48*512*512)

__device__ __forceinline__ void get_weights(float* w) {
    float s = 0.f;
#pragma unroll
    for (int i = 0; i < 11; ++i) {
        float d = (float)(i - 5);
        w[i] = expf(-(d * d) / 4.5f);
        s += w[i];
    }
    float inv = 1.f / s;
#pragma unroll
    for (int i = 0; i < 11; ++i) w[i] *= inv;
}

__device__ __forceinline__ void load4g(const float* __restrict__ row, int gx,
                                       float* dst) {
    if (gx >= 0 && gx + 3 < IMG) {
        float4 v = *reinterpret_cast<const float4*>(row + gx);
        dst[0] = v.x; dst[1] = v.y; dst[2] = v.z; dst[3] = v.w;
    } else {
#pragma unroll
        for (int j = 0; j < 4; ++j)
            dst[j] = ((unsigned)(gx + j) < (unsigned)IMG) ? row[gx + j] : 0.f;
    }
}

__global__ void __launch_bounds__(256)
ssim_kernel(const float* __restrict__ img1,
            const float* __restrict__ img2,
            float* __restrict__ acc)
{
    __shared__ __align__(16) float h[5][LTY][TSX];   // 52.5 KiB stats
    __shared__ float wsum[4];

    float w[11];
    get_weights(w);

    const int tid = threadIdx.x;
    const int bx  = blockIdx.x;
    const int by  = blockIdx.y;
    const size_t pbase = (size_t)blockIdx.z * IMG * IMG;
    const float* __restrict__ p1 = img1 + pbase;
    const float* __restrict__ p2 = img2 + pbase;

    // ---------- Phase A: horizontal 11-tap, 4 output cols per item ----------
    for (int i = tid; i < LTY * 16; i += 256) {
        const int r     = i >> 4;
        const int g     = i & 15;
        const int cbase = g * 4;
        const int gy    = by * TSY - 5 + r;

        float in1[20], in2[20];
        if ((unsigned)gy < (unsigned)IMG) {
            const float* row1 = p1 + (size_t)gy * IMG;
            const float* row2 = p2 + (size_t)gy * IMG;
            const int gx0 = bx * TSX + cbase - 8;
#pragma unroll
            for (int b = 0; b < 5; ++b) {
                load4g(row1, gx0 + b * 4, &in1[b * 4]);
                load4g(row2, gx0 + b * 4, &in2[b * 4]);
            }
        } else {
#pragma unroll
            for (int t = 0; t < 20; ++t) { in1[t] = 0.f; in2[t] = 0.f; }
        }

        float s11[14], s22[14], s12[14];
#pragma unroll
        for (int t = 0; t < 14; ++t) {
            float a = in1[t + 3], b = in2[t + 3];
            s11[t] = a * a;
            s22[t] = b * b;
            s12[t] = a * b;
        }

        float m1v[4], m2v[4], a11v[4], a22v[4], a12v[4];
#pragma unroll
        for (int q = 0; q < 4; ++q) {
            float m1 = 0.f, m2 = 0.f, a11 = 0.f, a22 = 0.f, a12 = 0.f;
#pragma unroll
            for (int k = 0; k < 11; ++k) {
                float wk = w[k];
                m1  += wk * in1[3 + q + k];
                m2  += wk * in2[3 + q + k];
                a11 += wk * s11[q + k];
                a22 += wk * s22[q + k];
                a12 += wk * s12[q + k];
            }
            m1v[q] = m1; m2v[q] = m2; a11v[q] = a11; a22v[q] = a22; a12v[q] = a12;
        }
        *reinterpret_cast<float4*>(&h[0][r][cbase]) = make_float4(m1v[0],  m1v[1],  m1v[2],  m1v[3]);
        *reinterpret_cast<float4*>(&h[1][r][cbase]) = make_float4(m2v[0],  m2v[1],  m2v[2],  m2v[3]);
        *reinterpret_cast<float4*>(&h[2][r][cbase]) = make_float4(a11v[0], a11v[1], a11v[2], a11v[3]);
        *reinterpret_cast<float4*>(&h[3][r][cbase]) = make_float4(a22v[0], a22v[1], a22v[2], a22v[3]);
        *reinterpret_cast<float4*>(&h[4][r][cbase]) = make_float4(a12v[0], a12v[1], a12v[2], a12v[3]);
    }
    __syncthreads();

    // ---------- Phase B: vertical 11-tap + SSIM, 2 cols x 4 rows per thread --
    const float C1 = 1e-4f;
    const float C2 = 9e-4f;
    float local = 0.f;
    {
        const int cg = tid & 31;       // column pair: cols cg*2, cg*2+1
        const int rg = tid >> 5;       // 0..7 -> output rows rg*4 .. rg*4+3
        const int c2 = cg * 2;
        const int r0 = rg * 4;

        float ac[4][5][2];
#pragma unroll
        for (int q = 0; q < 4; ++q)
#pragma unroll
            for (int s = 0; s < 5; ++s) {
                ac[q][s][0] = 0.f; ac[q][s][1] = 0.f;
            }

#pragma unroll
        for (int rr = 0; rr < 14; ++rr) {
            float2 hv[5];
#pragma unroll
            for (int s = 0; s < 5; ++s)
                hv[s] = *reinterpret_cast<const float2*>(&h[s][r0 + rr][c2]);
#pragma unroll
            for (int q = 0; q < 4; ++q) {
                if (rr - q >= 0 && rr - q <= 10) {   // compile-time after unroll
                    const float wk = w[rr - q];
#pragma unroll
                    for (int s = 0; s < 5; ++s) {
                        ac[q][s][0] += wk * hv[s].x;
                        ac[q][s][1] += wk * hv[s].y;
                    }
                }
            }
        }

#pragma unroll
        for (int q = 0; q < 4; ++q) {
#pragma unroll
            for (int c = 0; c < 2; ++c) {
                float mu1 = ac[q][0][c], mu2 = ac[q][1][c];
                float v11 = ac[q][2][c], v22 = ac[q][3][c], v12 = ac[q][4][c];
                float mu1sq = mu1 * mu1;
                float mu2sq = mu2 * mu2;
                float mu12  = mu1 * mu2;
                float sig1  = v11 - mu1sq;
                float sig2  = v22 - mu2sq;
                float sig12 = v12 - mu12;
                float num = (2.f * mu12 + C1) * (2.f * sig12 + C2);
                float den = (mu1sq + mu2sq + C1) * (sig1 + sig2 + C2);
                local += num / den;
            }
        }
    }

    // ---------- block reduction ----------
#pragma unroll
    for (int off = 32; off > 0; off >>= 1)
        local += __shfl_down(local, off, 64);
    if ((tid & 63) == 0) wsum[tid >> 6] = local;
    __syncthreads();
    if (tid == 0) {
        float t = wsum[0] + wsum[1] + wsum[2] + wsum[3];
        atomicAdd(acc, t);
    }
}

__global__ void zero_acc_kernel(float* acc) {
    if (threadIdx.x == 0) acc[0] = 0.f;
}

__global__ void finalize_kernel(const float* __restrict__ acc,
                                float* __restrict__ out) {
    if (threadIdx.x == 0)
        out[0] = 1.0f - acc[0] * (1.0f / (float)NPIX);
}

extern "C" void kernel_launch(void* const* d_in, const int* in_sizes, int n_in,
                              void* d_out, int out_size, void* d_ws, size_t ws_size,
                              hipStream_t stream) {
    const float* img1 = (const float*)d_in[0];
    const float* img2 = (const float*)d_in[1];
    float* out = (float*)d_out;
    float* acc = (float*)d_ws;

    zero_acc_kernel<<<1, 64, 0, stream>>>(acc);
    dim3 grid(IMG / TSX, IMG / TSY, NPLANES);   // (8, 16, 48) = 6144 blocks
    ssim_kernel<<<grid, 256, 0, stream>>>(img1, img2, acc);
    finalize_kernel<<<1, 64, 0, stream>>>(acc, out);
}

// Round 6
// 217.509 us; speedup vs baseline: 2.0719x; 1.1309x over previous
//
#include <hip/hip_runtime.h>
#include <hip/hip_fp16.h>
#include <math.h>

// SSIM loss v5: v4 structure with fp16-packed LDS h-stats (LDS 52.5KB ->
// 26.9KB => 6 blocks/CU) and packed-half2 vertical conv (v_pk_fma_f16,
// half the phase-B FMA). Phase A fp32 horizontal conv, cvt_pkrtz pack.
// Inputs: img1, img2 float32 [16,3,512,512]. Output: scalar float32.

#define TSX   64
#define TSY   32
#define LTY   42               // TSY + 10 rows of horizontal stats
#define IMG   512
#define NPLANES 48
#define NPIX  (48*512*512)

union H2Pack { __half2 h[2]; uint2 u; };

__device__ __forceinline__ void get_weights(float* w) {
    float s = 0.f;
#pragma unroll
    for (int i = 0; i < 11; ++i) {
        float d = (float)(i - 5);
        w[i] = expf(-(d * d) / 4.5f);
        s += w[i];
    }
    float inv = 1.f / s;
#pragma unroll
    for (int i = 0; i < 11; ++i) w[i] *= inv;
}

__device__ __forceinline__ void load4g(const float* __restrict__ row, int gx,
                                       float* dst) {
    if (gx >= 0 && gx + 3 < IMG) {
        float4 v = *reinterpret_cast<const float4*>(row + gx);
        dst[0] = v.x; dst[1] = v.y; dst[2] = v.z; dst[3] = v.w;
    } else {
#pragma unroll
        for (int j = 0; j < 4; ++j)
            dst[j] = ((unsigned)(gx + j) < (unsigned)IMG) ? row[gx + j] : 0.f;
    }
}

__global__ void __launch_bounds__(256, 6)
ssim_kernel(const float* __restrict__ img1,
            const float* __restrict__ img2,
            float* __restrict__ acc)
{
    __shared__ __align__(16) __half2 hh[5][LTY][TSX / 2];   // 26.25 KiB
    __shared__ float wsum[4];

    float w[11];
    get_weights(w);

    const int tid = threadIdx.x;
    const int bx  = blockIdx.x;
    const int by  = blockIdx.y;
    const size_t pbase = (size_t)blockIdx.z * IMG * IMG;
    const float* __restrict__ p1 = img1 + pbase;
    const float* __restrict__ p2 = img2 + pbase;

    const bool interior_x = (bx >= 1 && bx <= 6);   // block-uniform (scalar)

    // ---------- Phase A: horizontal 11-tap, 4 output cols per item ----------
    for (int i = tid; i < LTY * 16; i += 256) {
        const int r     = i >> 4;
        const int g     = i & 15;
        const int cbase = g * 4;
        const int gy    = by * TSY - 5 + r;

        float in1[20], in2[20];
        if ((unsigned)gy < (unsigned)IMG) {
            const float* row1 = p1 + (size_t)gy * IMG;
            const float* row2 = p2 + (size_t)gy * IMG;
            const int gx0 = bx * TSX + cbase - 8;
            if (interior_x) {
#pragma unroll
                for (int b = 0; b < 5; ++b) {
                    float4 v = *reinterpret_cast<const float4*>(row1 + gx0 + b * 4);
                    in1[b*4+0] = v.x; in1[b*4+1] = v.y; in1[b*4+2] = v.z; in1[b*4+3] = v.w;
                    float4 u = *reinterpret_cast<const float4*>(row2 + gx0 + b * 4);
                    in2[b*4+0] = u.x; in2[b*4+1] = u.y; in2[b*4+2] = u.z; in2[b*4+3] = u.w;
                }
            } else {
#pragma unroll
                for (int b = 0; b < 5; ++b) {
                    load4g(row1, gx0 + b * 4, &in1[b * 4]);
                    load4g(row2, gx0 + b * 4, &in2[b * 4]);
                }
            }
        } else {
#pragma unroll
            for (int t = 0; t < 20; ++t) { in1[t] = 0.f; in2[t] = 0.f; }
        }

        float s11[14], s22[14], s12[14];
#pragma unroll
        for (int t = 0; t < 14; ++t) {
            float a = in1[t + 3], b = in2[t + 3];
            s11[t] = a * a;
            s22[t] = b * b;
            s12[t] = a * b;
        }

        float m1v[4], m2v[4], a11v[4], a22v[4], a12v[4];
#pragma unroll
        for (int q = 0; q < 4; ++q) {
            float m1 = 0.f, m2 = 0.f, a11 = 0.f, a22 = 0.f, a12 = 0.f;
#pragma unroll
            for (int k = 0; k < 11; ++k) {
                float wk = w[k];
                m1  += wk * in1[3 + q + k];
                m2  += wk * in2[3 + q + k];
                a11 += wk * s11[q + k];
                a22 += wk * s22[q + k];
                a12 += wk * s12[q + k];
            }
            m1v[q] = m1; m2v[q] = m2; a11v[q] = a11; a22v[q] = a22; a12v[q] = a12;
        }

        H2Pack pk;
        pk.h[0] = __floats2half2_rn(m1v[0],  m1v[1]);
        pk.h[1] = __floats2half2_rn(m1v[2],  m1v[3]);
        *reinterpret_cast<uint2*>(&hh[0][r][2 * g]) = pk.u;
        pk.h[0] = __floats2half2_rn(m2v[0],  m2v[1]);
        pk.h[1] = __floats2half2_rn(m2v[2],  m2v[3]);
        *reinterpret_cast<uint2*>(&hh[1][r][2 * g]) = pk.u;
        pk.h[0] = __floats2half2_rn(a11v[0], a11v[1]);
        pk.h[1] = __floats2half2_rn(a11v[2], a11v[3]);
        *reinterpret_cast<uint2*>(&hh[2][r][2 * g]) = pk.u;
        pk.h[0] = __floats2half2_rn(a22v[0], a22v[1]);
        pk.h[1] = __floats2half2_rn(a22v[2], a22v[3]);
        *reinterpret_cast<uint2*>(&hh[3][r][2 * g]) = pk.u;
        pk.h[0] = __floats2half2_rn(a12v[0], a12v[1]);
        pk.h[1] = __floats2half2_rn(a12v[2], a12v[3]);
        *reinterpret_cast<uint2*>(&hh[4][r][2 * g]) = pk.u;
    }
    __syncthreads();

    // ----- Phase B: vertical 11-tap (packed half2 FMA) + SSIM, 4c x 2r -----
    const float C1 = 1e-4f;
    const float C2 = 9e-4f;
    float local = 0.f;
    {
        const int cg = tid & 15;       // half2 cols 2cg,2cg+1 (px cols 4cg..4cg+3)
        const int rg = tid >> 4;       // 0..15 -> output rows rg*2, rg*2+1
        const int r0 = rg * 2;

        __half2 wh[11];
#pragma unroll
        for (int k = 0; k < 11; ++k) wh[k] = __float2half2_rn(w[k]);

        const __half2 zero2 = __float2half2_rn(0.f);
        __half2 ac[2][5][2];
#pragma unroll
        for (int q = 0; q < 2; ++q)
#pragma unroll
            for (int s = 0; s < 5; ++s) {
                ac[q][s][0] = zero2; ac[q][s][1] = zero2;
            }

#pragma unroll
        for (int rr = 0; rr < 12; ++rr) {
            H2Pack rd[5];
#pragma unroll
            for (int s = 0; s < 5; ++s)
                rd[s].u = *reinterpret_cast<const uint2*>(&hh[s][r0 + rr][2 * cg]);
#pragma unroll
            for (int q = 0; q < 2; ++q) {
                const int k = rr - q;
                if (k >= 0 && k <= 10) {             // compile-time after unroll
                    const __half2 wk = wh[k];
#pragma unroll
                    for (int s = 0; s < 5; ++s) {
                        ac[q][s][0] = __hfma2(wk, rd[s].h[0], ac[q][s][0]);
                        ac[q][s][1] = __hfma2(wk, rd[s].h[1], ac[q][s][1]);
                    }
                }
            }
        }

#pragma unroll
        for (int q = 0; q < 2; ++q) {
#pragma unroll
            for (int hp = 0; hp < 2; ++hp) {
                float2 mu1 = __half22float2(ac[q][0][hp]);
                float2 mu2 = __half22float2(ac[q][1][hp]);
                float2 v11 = __half22float2(ac[q][2][hp]);
                float2 v22 = __half22float2(ac[q][3][hp]);
                float2 v12 = __half22float2(ac[q][4][hp]);
#pragma unroll
                for (int e = 0; e < 2; ++e) {
                    float m1 = e ? mu1.y : mu1.x;
                    float m2 = e ? mu2.y : mu2.x;
                    float s1 = e ? v11.y : v11.x;
                    float s2 = e ? v22.y : v22.x;
                    float sx = e ? v12.y : v12.x;
                    float mu1sq = m1 * m1;
                    float mu2sq = m2 * m2;
                    float mu12  = m1 * m2;
                    float sig1  = s1 - mu1sq;
                    float sig2  = s2 - mu2sq;
                    float sig12 = sx - mu12;
                    float num = (2.f * mu12 + C1) * (2.f * sig12 + C2);
                    float den = (mu1sq + mu2sq + C1) * (sig1 + sig2 + C2);
                    local += num / den;
                }
            }
        }
    }

    // ---------- block reduction ----------
#pragma unroll
    for (int off = 32; off > 0; off >>= 1)
        local += __shfl_down(local, off, 64);
    if ((tid & 63) == 0) wsum[tid >> 6] = local;
    __syncthreads();
    if (tid == 0) {
        float t = wsum[0] + wsum[1] + wsum[2] + wsum[3];
        atomicAdd(acc, t);
    }
}

__global__ void zero_acc_kernel(float* acc) {
    if (threadIdx.x == 0) acc[0] = 0.f;
}

__global__ void finalize_kernel(const float* __restrict__ acc,
                                float* __restrict__ out) {
    if (threadIdx.x == 0)
        out[0] = 1.0f - acc[0] * (1.0f / (float)NPIX);
}

extern "C" void kernel_launch(void* const* d_in, const int* in_sizes, int n_in,
                              void* d_out, int out_size, void* d_ws, size_t ws_size,
                              hipStream_t stream) {
    const float* img1 = (const float*)d_in[0];
    const float* img2 = (const float*)d_in[1];
    float* out = (float*)d_out;
    float* acc = (float*)d_ws;

    zero_acc_kernel<<<1, 64, 0, stream>>>(acc);
    dim3 grid(IMG / TSX, IMG / TSY, NPLANES);   // (8, 16, 48) = 6144 blocks
    ssim_kernel<<<grid, 256, 0, stream>>>(img1, img2, acc);
    finalize_kernel<<<1, 64, 0, stream>>>(acc, out);
}